// Round 1
// baseline (9407.661 us; speedup 1.0000x reference)
//
#include <hip/hip_runtime.h>

typedef __bf16 bf16;
typedef bf16 bf16x8 __attribute__((ext_vector_type(8)));
typedef float f32x4 __attribute__((ext_vector_type(4)));

#define DEVFN __device__ __forceinline__

constexpr int cV = 50000, cE = 256, cH = 512, cM = 100, cH2 = 256;
constexpr int cB = 64, cS = 400, cT = 25, cEOS = 2;
constexpr int cSB = cS * cB;          // 25600
constexpr int cG2 = 3 * cH2;          // 768
constexpr int cKcat = 1280;           // [c(512) | wemb(256) | h(512)]
constexpr int cN4 = 2048;             // r,z,inn,hn rows
constexpr int cNTV = (cV + 63) / 64;  // 782

struct GArgs {
  const bf16* A; const bf16* Bw; const float* bias;
  float* outF; bf16* outBf;
  const float* auxF; const bf16* auxBf;
  float* partials;
  int M, N, K, ldo;
};

DEVFN float sigm(float x) { return 1.f / (1.f + __expf(-x)); }

// ---------------- generic 64x64-per-wave MFMA GEMM: C = A(MxK) * B(NxK)^T ----------------
template <int EPI>
__global__ __launch_bounds__(256) void gemm64_k(GArgs g) {
  const int tid = threadIdx.x;
  const int w = blockIdx.x * 4 + (tid >> 6);
  const int tM = g.M >> 6;
  const int tN = (g.N + 63) >> 6;
  if (w >= tM * tN) return;
  const int im = w % tM, in = w / tM;
  const int m0 = im << 6, n0 = in << 6;
  const int lane = tid & 63, lr = lane & 15, lh = lane >> 4;

  f32x4 acc[4][4];
#pragma unroll
  for (int i = 0; i < 4; ++i)
#pragma unroll
    for (int j = 0; j < 4; ++j)
#pragma unroll
      for (int r = 0; r < 4; ++r) acc[i][j][r] = 0.f;

  bf16x8 bz;
#pragma unroll
  for (int q = 0; q < 8; ++q) bz[q] = (bf16)0.f;

  const int K = g.K;
  for (int k0 = 0; k0 < K; k0 += 32) {
    bf16x8 av[4], bw[4];
#pragma unroll
    for (int mt = 0; mt < 4; ++mt)
      av[mt] = *(const bf16x8*)(g.A + (size_t)(m0 + mt * 16 + lr) * K + k0 + lh * 8);
#pragma unroll
    for (int nt = 0; nt < 4; ++nt) {
      int row = n0 + nt * 16 + lr;
      bw[nt] = (row < g.N) ? *(const bf16x8*)(g.Bw + (size_t)row * K + k0 + lh * 8) : bz;
    }
#pragma unroll
    for (int mt = 0; mt < 4; ++mt)
#pragma unroll
      for (int nt = 0; nt < 4; ++nt)
        acc[mt][nt] = __builtin_amdgcn_mfma_f32_16x16x32_bf16(av[mt], bw[nt], acc[mt][nt], 0, 0, 0);
  }

  if constexpr (EPI == 3) {
    // per-row (mx, sumexp) partials over this 64-col tile
#pragma unroll
    for (int mt = 0; mt < 4; ++mt) {
#pragma unroll
      for (int r = 0; r < 4; ++r) {
        const int m = m0 + mt * 16 + lh * 4 + r;
        float vv[4];
        float mx = -3.4e38f;
#pragma unroll
        for (int nt = 0; nt < 4; ++nt) {
          int n = n0 + nt * 16 + lr;
          float v = (n < g.N) ? (acc[mt][nt][r] + g.bias[n]) : -3.4e38f;
          vv[nt] = v;
          mx = fmaxf(mx, v);
        }
#pragma unroll
        for (int msk = 1; msk < 16; msk <<= 1) mx = fmaxf(mx, __shfl_xor(mx, msk));
        float sm = 0.f;
#pragma unroll
        for (int nt = 0; nt < 4; ++nt) {
          int n = n0 + nt * 16 + lr;
          if (n < g.N) sm += __expf(vv[nt] - mx);
        }
#pragma unroll
        for (int msk = 1; msk < 16; msk <<= 1) sm += __shfl_xor(sm, msk);
        if (lr == 0) {
          float* p = g.partials + ((size_t)in * 64 + m) * 2;
          p[0] = mx;
          p[1] = sm;
        }
      }
    }
  } else {
#pragma unroll
    for (int mt = 0; mt < 4; ++mt) {
#pragma unroll
      for (int nt = 0; nt < 4; ++nt) {
        const int n = n0 + nt * 16 + lr;
        if (n < g.N) {
          const float bia = g.bias[n];
#pragma unroll
          for (int r = 0; r < 4; ++r) {
            const int m = m0 + mt * 16 + lh * 4 + r;
            float v = acc[mt][nt][r] + bia;
            if constexpr (EPI == 0) {
              g.outF[(size_t)m * g.ldo + n] = v;
            } else {  // EPI==1: sgate epilogue
              float sg = sigm(v + g.auxF[(size_t)(m & 63) * g.ldo + n]);
              float st = (float)g.auxBf[(size_t)m * g.ldo + n];
              g.outBf[(size_t)m * g.ldo + n] = (bf16)(sg * st);
            }
          }
        }
      }
    }
  }
}

// ---------------- small prep kernels ----------------
__global__ void f2b_k(const float* __restrict__ x, bf16* __restrict__ y, int n) {
  int i = blockIdx.x * 256 + threadIdx.x;
  if (i < n) y[i] = (bf16)x[i];
}

__global__ void init_k(bf16* hbf_all, float* hf_all, unsigned* scal) {
  int i = blockIdx.x * 256 + threadIdx.x;
  if (i < 4 * cB * cH2) { hbf_all[i] = (bf16)0.f; hf_all[i] = 0.f; }
  if (i < 16) scal[i] = 0u;
}

__global__ void gather_k(const int* __restrict__ src, const float* __restrict__ emb,
                         bf16* __restrict__ embeds) {
  int i = blockIdx.x * 256 + threadIdx.x;  // over S*B*E
  int e = i & 255;
  int sb = i >> 8;
  int s = sb >> 6, b = sb & 63;
  int tok = src[b * cS + s];
  embeds[i] = (bf16)emb[(size_t)tok * cE + e];
}

__global__ void build_wp_k(const float* __restrict__ Wih_c, const float* __restrict__ Whh_c,
                           const float* __restrict__ bih_c, const float* __restrict__ bhh_c,
                           bf16* __restrict__ Wp, float* __restrict__ bp) {
  int i = blockIdx.x * 256 + threadIdx.x;  // over 2048*1280
  if (i >= cN4 * cKcat) return;
  int j = i / cKcat, c = i % cKcat;
  float v;
  if (j < 1024) v = (c < 768) ? Wih_c[(size_t)j * 768 + c] : Whh_c[(size_t)j * 512 + (c - 768)];
  else if (j < 1536) v = (c < 768) ? Wih_c[(size_t)j * 768 + c] : 0.f;
  else v = (c < 768) ? 0.f : Whh_c[(size_t)(j - 512) * 512 + (c - 768)];
  Wp[i] = (bf16)v;
  if (c == 0) {
    float bb;
    if (j < 1024) bb = bih_c[j] + bhh_c[j];
    else if (j < 1536) bb = bih_c[j];
    else bb = bhh_c[j - 512];
    bp[j] = bb;
  }
}

__global__ void concat_k(const float* __restrict__ hf, const float* __restrict__ hb,
                         bf16* __restrict__ hd_bf, float* __restrict__ hd_f) {
  int i = blockIdx.x * 256 + threadIdx.x;  // 64*512
  if (i >= cB * cH) return;
  int b = i >> 9, k = i & 511;
  float v = (k < 256) ? hf[b * 256 + k] : hb[b * 256 + (k - 256)];
  hd_bf[i] = (bf16)v;
  hd_f[i] = v;
}

// ---------------- persistent encoder GRU (8 blocks: 4/dir, spin barrier per step) ----------------
__global__ __launch_bounds__(256, 1) void enc_rnn_k(
    const bf16* __restrict__ WhhF, const bf16* __restrict__ WhhB,
    const float* __restrict__ giF, const float* __restrict__ giB,
    const float* __restrict__ bhhF, const float* __restrict__ bhhB,
    bf16* __restrict__ hbf_all, float* __restrict__ hf_all,
    bf16* __restrict__ states, unsigned* __restrict__ bar) {
  const int blk = blockIdx.x;
  const int dir = blk >> 2;
  const int qb = blk & 3;  // hidden quarter [qb*64, qb*64+64)
  const bf16* Whh = dir ? WhhB : WhhF;
  const float* gi = dir ? giB : giF;
  const float* bhh = dir ? bhhB : bhhF;
  unsigned* ctr = bar + dir;

  const int tid = threadIdx.x;
  const int lane = tid & 63, w = tid >> 6;
  const int wm = w & 1, wn = w >> 1;
  const int lr = lane & 15, lh = lane >> 4;
  const int u0a = qb * 64 + wn * 32;
  const int m0 = wm * 32;

  // register-resident Whh fragments for this wave's 32 hidden units (r,z,n rows)
  bf16x8 Bf[6][8];
  float bh[6];
#pragma unroll
  for (int gg = 0; gg < 3; ++gg)
#pragma unroll
    for (int ut = 0; ut < 2; ++ut) {
      int nbase = gg * 256 + u0a + ut * 16;
#pragma unroll
      for (int kf = 0; kf < 8; ++kf)
        Bf[gg * 2 + ut][kf] = *(const bf16x8*)(Whh + (size_t)(nbase + lr) * 256 + kf * 32 + lh * 8);
      bh[gg * 2 + ut] = bhh[nbase + lr];
    }

  __shared__ bf16 hs[64][264];  // padded rows

  for (int t = 0; t < cS; ++t) {
    const bf16* hrd = hbf_all + ((dir << 1) | (t & 1)) * (cB * cH2);
    bf16* hwr = hbf_all + ((dir << 1) | ((t + 1) & 1)) * (cB * cH2);
    const float* hfrd = hf_all + ((dir << 1) | (t & 1)) * (cB * cH2);
    float* hfwr = hf_all + ((dir << 1) | ((t + 1) & 1)) * (cB * cH2);

    // stage h (bf16) -> LDS
    for (int c = tid; c < 2048; c += 256) {
      int row = c >> 5, col = c & 31;
      *(bf16x8*)(&hs[row][col * 8]) = *(const bf16x8*)(hrd + row * 256 + col * 8);
    }
    __syncthreads();

    f32x4 acc[2][6];
#pragma unroll
    for (int i = 0; i < 2; ++i)
#pragma unroll
      for (int j = 0; j < 6; ++j)
#pragma unroll
        for (int r = 0; r < 4; ++r) acc[i][j][r] = 0.f;

#pragma unroll
    for (int mt = 0; mt < 2; ++mt) {
      bf16x8 av[8];
#pragma unroll
      for (int kf = 0; kf < 8; ++kf)
        av[kf] = *(const bf16x8*)(&hs[m0 + mt * 16 + lr][kf * 32 + lh * 8]);
#pragma unroll
      for (int nt = 0; nt < 6; ++nt)
#pragma unroll
        for (int kf = 0; kf < 8; ++kf)
          acc[mt][nt] = __builtin_amdgcn_mfma_f32_16x16x32_bf16(av[kf], Bf[nt][kf], acc[mt][nt], 0, 0, 0);
    }

    const int s_src = dir ? (cS - 1 - t) : t;
    const float* gis = gi + (size_t)s_src * (cB * cG2);
#pragma unroll
    for (int mt = 0; mt < 2; ++mt)
#pragma unroll
      for (int ut = 0; ut < 2; ++ut) {
        const int u = u0a + ut * 16 + lr;
#pragma unroll
        for (int r = 0; r < 4; ++r) {
          const int b = m0 + mt * 16 + lh * 4 + r;
          float gir = gis[b * cG2 + u];
          float giz = gis[b * cG2 + 256 + u];
          float gin = gis[b * cG2 + 512 + u];
          float hold = hfrd[b * 256 + u];
          float rr = sigm(gir + acc[mt][ut][r] + bh[ut]);
          float zz = sigm(giz + acc[mt][2 + ut][r] + bh[2 + ut]);
          float nn = tanhf(gin + rr * (acc[mt][4 + ut][r] + bh[4 + ut]));
          float hnew = (1.f - zz) * nn + zz * hold;
          hfwr[b * 256 + u] = hnew;
          bf16 hb16 = (bf16)hnew;
          hwr[b * 256 + u] = hb16;
          states[((size_t)s_src * cB + b) * cH + dir * 256 + u] = hb16;
        }
      }

    __threadfence();
    __syncthreads();
    if (tid == 0) {
      __hip_atomic_fetch_add(ctr, 1u, __ATOMIC_ACQ_REL, __HIP_MEMORY_SCOPE_AGENT);
      const unsigned target = 4u * (unsigned)(t + 1);
      while (__hip_atomic_load(ctr, __ATOMIC_ACQUIRE, __HIP_MEMORY_SCOPE_AGENT) < target)
        __builtin_amdgcn_s_sleep(1);
    }
    __syncthreads();
    __threadfence();
  }
}

// ---------------- decoder: attention + context + build xh ----------------
__global__ __launch_bounds__(256) void attn_k(
    const bf16* __restrict__ hin, const float* __restrict__ Wd, const float* __restrict__ bd,
    const float* __restrict__ Wo, const float* __restrict__ bo,
    const float* __restrict__ encproj, const bf16* __restrict__ statesg,
    const float* __restrict__ emb, const int* __restrict__ trg, int step,
    bf16* __restrict__ xh) {
  const int b = blockIdx.x, tid = threadIdx.x;
  const int lane = tid & 63, wid = tid >> 6;
  __shared__ float hsh[512];
  __shared__ float dsh[100];
  __shared__ float esh[400];
  __shared__ float red[16];

  for (int k = tid; k < 512; k += 256) hsh[k] = (float)hin[b * 512 + k];
  __syncthreads();
  if (tid < 100) {
    float a = bd[tid];
    const float* wr = Wd + (size_t)tid * 512;
    for (int k = 0; k < 512; ++k) a += hsh[k] * wr[k];
    dsh[tid] = a;
  }
  __syncthreads();

  const float bo0 = bo[0];
  float e0, e1 = -3.4e38f;
  {
    const float* ep = encproj + ((size_t)tid * cB + b) * cM;
    float a = bo0;
    for (int j = 0; j < 100; ++j) a += Wo[j] * tanhf(dsh[j] + ep[j]);
    e0 = a;
  }
  if (tid < 144) {
    const float* ep = encproj + ((size_t)(tid + 256) * cB + b) * cM;
    float a = bo0;
    for (int j = 0; j < 100; ++j) a += Wo[j] * tanhf(dsh[j] + ep[j]);
    e1 = a;
  }
  float mx = fmaxf(e0, e1);
#pragma unroll
  for (int msk = 1; msk < 64; msk <<= 1) mx = fmaxf(mx, __shfl_xor(mx, msk));
  if (lane == 0) red[wid] = mx;
  __syncthreads();
  mx = fmaxf(fmaxf(red[0], red[1]), fmaxf(red[2], red[3]));

  float a0 = __expf(e0 - mx);
  float a1 = (tid < 144) ? __expf(e1 - mx) : 0.f;
  esh[tid] = a0;
  if (tid < 144) esh[tid + 256] = a1;
  float sm = a0 + a1;
#pragma unroll
  for (int msk = 1; msk < 64; msk <<= 1) sm += __shfl_xor(sm, msk);
  if (lane == 0) red[8 + wid] = sm;
  __syncthreads();
  const float inv = 1.f / (red[8] + red[9] + red[10] + red[11]);

  for (int k = tid; k < 512; k += 256) {
    float a = 0.f;
    const bf16* sp = statesg + b * cH + k;
    for (int s = 0; s < cS; ++s) a += esh[s] * (float)sp[(size_t)s * (cB * cH)];
    xh[b * cKcat + k] = (bf16)(a * inv);
  }
  const int tok = trg[b * cT + step];
  xh[b * cKcat + 512 + tid] = (bf16)emb[(size_t)tok * cE + tid];
  for (int k = tid; k < 512; k += 256) xh[b * cKcat + 768 + k] = hin[b * 512 + k];
}

__global__ __launch_bounds__(256) void gru_gate_k(const float* __restrict__ g4,
                                                  const float* __restrict__ hin_f,
                                                  float* __restrict__ hout_f,
                                                  bf16* __restrict__ hout_bf) {
  int i = blockIdx.x * 256 + threadIdx.x;
  if (i >= cB * cH) return;
  int b = i >> 9, t = i & 511;
  const float* gb = g4 + (size_t)b * cN4;
  float r = sigm(gb[t]);
  float z = sigm(gb[512 + t]);
  float n = tanhf(gb[1024 + t] + r * gb[1536 + t]);
  float h2 = (1.f - z) * n + z * hin_f[i];
  hout_f[i] = h2;
  hout_bf[i] = (bf16)h2;
}

// ---------------- per-step loss reduce (1 block, 1024 threads) ----------------
__global__ __launch_bounds__(1024) void loss_k(const float* __restrict__ partials,
                                               const bf16* __restrict__ h2,
                                               const float* __restrict__ Wv,
                                               const float* __restrict__ bv,
                                               const int* __restrict__ trg, int step,
                                               float* __restrict__ accum,
                                               float* __restrict__ out) {
  const int tid = threadIdx.x;
  const int row = tid >> 4, j = tid & 15;
  float mx = -3.4e38f, sm = 0.f;
  for (int p = j; p < cNTV; p += 16) {
    const float* pp = partials + ((size_t)p * 64 + row) * 2;
    float m2 = pp[0], s2 = pp[1];
    if (m2 > mx) { sm = sm * __expf(mx - m2) + s2; mx = m2; }
    else sm += s2 * __expf(m2 - mx);
  }
#pragma unroll
  for (int msk = 1; msk < 16; msk <<= 1) {
    float om = __shfl_xor(mx, msk), os = __shfl_xor(sm, msk);
    if (om > mx) { sm = sm * __expf(mx - om) + os; mx = om; }
    else sm += os * __expf(om - mx);
  }
  const int tok = trg[row * cT + step];
  float dot = 0.f;
  const float* wr = Wv + (size_t)tok * cH;
  const bf16* hr = h2 + row * cH;
  for (int k = j * 32; k < j * 32 + 32; ++k) dot += (float)hr[k] * wr[k];
#pragma unroll
  for (int msk = 1; msk < 16; msk <<= 1) dot += __shfl_xor(dot, msk);

  __shared__ float wnll[64];
  __shared__ float wsh[64];
  if (j == 0) {
    float lse = mx + __logf(sm);
    float logit = dot + bv[tok];
    float nll = lse - logit;
    float wgt = (tok != cEOS) ? 1.f : 0.f;
    wnll[row] = wgt * nll;
    wsh[row] = wgt;
  }
  __syncthreads();
  if (tid == 0) {
    float a = 0.f, d = 0.f;
    for (int i = 0; i < 64; ++i) { a += wnll[i]; d += wsh[i]; }
    float sl = a / d;
    float tot = *accum + sl * (1.f / (float)cB);
    *accum = tot;
    if (step == cT - 2) out[0] = tot;
  }
}

// ---------------- host ----------------
extern "C" void kernel_launch(void* const* d_in, const int* in_sizes, int n_in,
                              void* d_out, int out_size, void* d_ws, size_t ws_size,
                              hipStream_t stream) {
  (void)in_sizes; (void)n_in; (void)out_size; (void)ws_size;
  const int* src = (const int*)d_in[0];
  const int* trg = (const int*)d_in[1];
  const float* emb = (const float*)d_in[2];
  const float* Wih_f = (const float*)d_in[3];
  const float* Whh_f = (const float*)d_in[4];
  const float* bih_f = (const float*)d_in[5];
  const float* bhh_f = (const float*)d_in[6];
  const float* Wih_b = (const float*)d_in[7];
  const float* Whh_b = (const float*)d_in[8];
  const float* bih_b = (const float*)d_in[9];
  const float* bhh_b = (const float*)d_in[10];
  const float* W1 = (const float*)d_in[11];
  const float* b1 = (const float*)d_in[12];
  const float* W2 = (const float*)d_in[13];
  const float* b2 = (const float*)d_in[14];
  const float* Wd = (const float*)d_in[15];
  const float* bd = (const float*)d_in[16];
  const float* We = (const float*)d_in[17];
  const float* be = (const float*)d_in[18];
  const float* Wo = (const float*)d_in[19];
  const float* bo = (const float*)d_in[20];
  const float* Wih_c = (const float*)d_in[21];
  const float* Whh_c = (const float*)d_in[22];
  const float* bih_c = (const float*)d_in[23];
  const float* bhh_c = (const float*)d_in[24];
  const float* Wv = (const float*)d_in[25];
  const float* bv = (const float*)d_in[26];
  float* out = (float*)d_out;

  char* ws = (char*)d_ws;
  size_t off = 0;
  auto carve = [&](size_t bytes) -> void* {
    void* p = ws + off;
    off += (bytes + 255) & ~(size_t)255;
    return p;
  };
  bf16* Wihf_b = (bf16*)carve((size_t)cG2 * cE * 2);
  bf16* Whhf_b = (bf16*)carve((size_t)cG2 * cH2 * 2);
  bf16* Wihb_b = (bf16*)carve((size_t)cG2 * cE * 2);
  bf16* Whhb_b = (bf16*)carve((size_t)cG2 * cH2 * 2);
  bf16* W1_b = (bf16*)carve((size_t)cH * cH * 2);
  bf16* W2_b = (bf16*)carve((size_t)cH * cH * 2);
  bf16* We_b = (bf16*)carve((size_t)cM * cH * 2);
  bf16* Wv_b = (bf16*)carve((size_t)cV * cH * 2);
  bf16* Wp_b = (bf16*)carve((size_t)cN4 * cKcat * 2);
  float* bp = (float*)carve((size_t)cN4 * 4);
  bf16* embeds = (bf16*)carve((size_t)cSB * cE * 2);
  float* gi_f = (float*)carve((size_t)cSB * cG2 * 4);
  float* gi_b = (float*)carve((size_t)cSB * cG2 * 4);
  bf16* states = (bf16*)carve((size_t)cSB * cH * 2);
  bf16* statesg = (bf16*)carve((size_t)cSB * cH * 2);
  bf16* hbf_all = (bf16*)carve((size_t)4 * cB * cH2 * 2);
  float* hf_all = (float*)carve((size_t)4 * cB * cH2 * 4);
  bf16* hdec0_bf = (bf16*)carve((size_t)cB * cH * 2);
  float* hdec0_f = (float*)carve((size_t)cB * cH * 4);
  bf16* hping_bf0 = (bf16*)carve((size_t)cB * cH * 2);
  bf16* hping_bf1 = (bf16*)carve((size_t)cB * cH * 2);
  float* hping_f0 = (float*)carve((size_t)cB * cH * 4);
  float* hping_f1 = (float*)carve((size_t)cB * cH * 4);
  float* hw2 = (float*)carve((size_t)cB * cH * 4);
  float* encproj = (float*)carve((size_t)cSB * cM * 4);
  bf16* xh = (bf16*)carve((size_t)cB * cKcat * 2);
  float* g4 = (float*)carve((size_t)cB * cN4 * 4);
  float* partials = (float*)carve((size_t)cNTV * 64 * 2 * 4);
  unsigned* scal = (unsigned*)carve(64);
  float* accum = (float*)(scal + 8);

  auto cvt = [&](const float* x, bf16* y, int n) {
    f2b_k<<<dim3((n + 255) / 256), dim3(256), 0, stream>>>(x, y, n);
  };
  auto gemm0 = [&](const bf16* A, const bf16* Bm, const float* bias, float* outF,
                   int M, int N, int K, int ldo) {
    GArgs ga{A, Bm, bias, outF, nullptr, nullptr, nullptr, nullptr, M, N, K, ldo};
    int waves = (M / 64) * ((N + 63) / 64);
    gemm64_k<0><<<dim3((waves + 3) / 4), dim3(256), 0, stream>>>(ga);
  };

  // init + weight prep
  init_k<<<dim3(256), dim3(256), 0, stream>>>(hbf_all, hf_all, scal);
  cvt(Wih_f, Wihf_b, cG2 * cE);
  cvt(Whh_f, Whhf_b, cG2 * cH2);
  cvt(Wih_b, Wihb_b, cG2 * cE);
  cvt(Whh_b, Whhb_b, cG2 * cH2);
  cvt(W1, W1_b, cH * cH);
  cvt(W2, W2_b, cH * cH);
  cvt(We, We_b, cM * cH);
  cvt(Wv, Wv_b, cV * cH);
  build_wp_k<<<dim3((cN4 * cKcat + 255) / 256), dim3(256), 0, stream>>>(Wih_c, Whh_c, bih_c, bhh_c, Wp_b, bp);

  // encoder
  gather_k<<<dim3(cSB * cE / 256), dim3(256), 0, stream>>>(src, emb, embeds);
  gemm0(embeds, Wihf_b, bih_f, gi_f, cSB, cG2, cE, cG2);
  gemm0(embeds, Wihb_b, bih_b, gi_b, cSB, cG2, cE, cG2);
  enc_rnn_k<<<dim3(8), dim3(256), 0, stream>>>(Whhf_b, Whhb_b, gi_f, gi_b, bhh_f, bhh_b,
                                               hbf_all, hf_all, states, scal);
  concat_k<<<dim3((cB * cH + 255) / 256), dim3(256), 0, stream>>>(
      hf_all + 0 * (cB * cH2), hf_all + 2 * (cB * cH2), hdec0_bf, hdec0_f);
  gemm0(hdec0_bf, W2_b, b2, hw2, cB, cH, cH, cH);
  {  // sgate: statesg = sigmoid(states@W1^T + b1 + hw2) * states
    GArgs ga{states, W1_b, b1, nullptr, statesg, hw2, states, nullptr, cSB, cH, cH, cH};
    int waves = (cSB / 64) * (cH / 64);
    gemm64_k<1><<<dim3((waves + 3) / 4), dim3(256), 0, stream>>>(ga);
  }
  gemm0(statesg, We_b, be, encproj, cSB, cM, cH, cM);

  // decoder
  for (int t = 0; t < cT - 1; ++t) {
    const bf16* hin_bf = (t == 0) ? hdec0_bf : ((t & 1) ? hping_bf0 : hping_bf1);
    const float* hin_f = (t == 0) ? hdec0_f : ((t & 1) ? hping_f0 : hping_f1);
    bf16* hout_bf = (t & 1) ? hping_bf1 : hping_bf0;
    float* hout_f = (t & 1) ? hping_f1 : hping_f0;

    attn_k<<<dim3(cB), dim3(256), 0, stream>>>(hin_bf, Wd, bd, Wo, bo, encproj, statesg,
                                               emb, trg, t, xh);
    gemm0(xh, Wp_b, bp, g4, cB, cN4, cKcat, cN4);
    gru_gate_k<<<dim3((cB * cH + 255) / 256), dim3(256), 0, stream>>>(g4, hin_f, hout_f, hout_bf);
    {  // logits partials
      GArgs ga{hout_bf, Wv_b, bv, nullptr, nullptr, nullptr, nullptr, partials, cB, cV, cH, 0};
      int waves = cNTV;  // 782
      gemm64_k<3><<<dim3((waves + 3) / 4), dim3(256), 0, stream>>>(ga);
    }
    loss_k<<<dim3(1), dim3(1024), 0, stream>>>(partials, hout_bf, Wv, bv, trg, t, accum, out);
  }
}

// Round 2
// 5686.274 us; speedup vs baseline: 1.6545x; 1.6545x over previous
//
#include <hip/hip_runtime.h>

typedef __bf16 bf16;
typedef bf16 bf16x8 __attribute__((ext_vector_type(8)));
typedef float f32x4 __attribute__((ext_vector_type(4)));

#define DEVFN __device__ __forceinline__

constexpr int cV = 50000, cE = 256, cH = 512, cM = 100, cH2 = 256;
constexpr int cB = 64, cS = 400, cT = 25, cEOS = 2;
constexpr int cSB = cS * cB;          // 25600
constexpr int cG2 = 3 * cH2;          // 768
constexpr int cKcat = 1280;           // [c(512) | wemb(256) | h(512)]
constexpr int cN4 = 2048;             // r,z,inn,hn rows
constexpr int cNTV = (cV + 63) / 64;  // 782

struct GArgs {
  const bf16* A; const bf16* Bw; const float* bias;
  float* outF; bf16* outBf;
  const float* auxF; const bf16* auxBf;
  float* partials;
  int M, N, K, ldo;
};

DEVFN float sigm(float x) { return 1.f / (1.f + __expf(-x)); }
DEVFN float tanh_f(float x) {
  float e2 = __expf(2.f * x);
  return 1.f - 2.f / (e2 + 1.f);
}

DEVFN void gload_lds16(const void* g, void* l) {
  __builtin_amdgcn_global_load_lds(
      (const __attribute__((address_space(1))) void*)g,
      (__attribute__((address_space(3))) void*)l, 16, 0, 0);
}

// ---------------- generic 64x64-per-wave MFMA GEMM: C = A(MxK) * B(NxK)^T ----------------
template <int EPI>
__global__ __launch_bounds__(256) void gemm64_k(GArgs g) {
  const int tid = threadIdx.x;
  const int w = blockIdx.x * 4 + (tid >> 6);
  const int tM = g.M >> 6;
  const int tN = (g.N + 63) >> 6;
  if (w >= tM * tN) return;
  const int im = w % tM, in = w / tM;
  const int m0 = im << 6, n0 = in << 6;
  const int lane = tid & 63, lr = lane & 15, lh = lane >> 4;

  f32x4 acc[4][4];
#pragma unroll
  for (int i = 0; i < 4; ++i)
#pragma unroll
    for (int j = 0; j < 4; ++j)
#pragma unroll
      for (int r = 0; r < 4; ++r) acc[i][j][r] = 0.f;

  bf16x8 bz;
#pragma unroll
  for (int q = 0; q < 8; ++q) bz[q] = (bf16)0.f;

  const int K = g.K;
  for (int k0 = 0; k0 < K; k0 += 32) {
    bf16x8 av[4], bw[4];
#pragma unroll
    for (int mt = 0; mt < 4; ++mt)
      av[mt] = *(const bf16x8*)(g.A + (size_t)(m0 + mt * 16 + lr) * K + k0 + lh * 8);
#pragma unroll
    for (int nt = 0; nt < 4; ++nt) {
      int row = n0 + nt * 16 + lr;
      bw[nt] = (row < g.N) ? *(const bf16x8*)(g.Bw + (size_t)row * K + k0 + lh * 8) : bz;
    }
#pragma unroll
    for (int mt = 0; mt < 4; ++mt)
#pragma unroll
      for (int nt = 0; nt < 4; ++nt)
        acc[mt][nt] = __builtin_amdgcn_mfma_f32_16x16x32_bf16(av[mt], bw[nt], acc[mt][nt], 0, 0, 0);
  }

  if constexpr (EPI == 3) {
    // per-row (mx, sumexp) partials over this 64-col tile
#pragma unroll
    for (int mt = 0; mt < 4; ++mt) {
#pragma unroll
      for (int r = 0; r < 4; ++r) {
        const int m = m0 + mt * 16 + lh * 4 + r;
        float vv[4];
        float mx = -3.4e38f;
#pragma unroll
        for (int nt = 0; nt < 4; ++nt) {
          int n = n0 + nt * 16 + lr;
          float v = (n < g.N) ? (acc[mt][nt][r] + g.bias[n]) : -3.4e38f;
          vv[nt] = v;
          mx = fmaxf(mx, v);
        }
#pragma unroll
        for (int msk = 1; msk < 16; msk <<= 1) mx = fmaxf(mx, __shfl_xor(mx, msk));
        float sm = 0.f;
#pragma unroll
        for (int nt = 0; nt < 4; ++nt) {
          int n = n0 + nt * 16 + lr;
          if (n < g.N) sm += __expf(vv[nt] - mx);
        }
#pragma unroll
        for (int msk = 1; msk < 16; msk <<= 1) sm += __shfl_xor(sm, msk);
        if (lr == 0) {
          float* p = g.partials + ((size_t)in * 64 + m) * 2;
          p[0] = mx;
          p[1] = sm;
        }
      }
    }
  } else {
#pragma unroll
    for (int mt = 0; mt < 4; ++mt) {
#pragma unroll
      for (int nt = 0; nt < 4; ++nt) {
        const int n = n0 + nt * 16 + lr;
        if (n < g.N) {
          const float bia = g.bias[n];
#pragma unroll
          for (int r = 0; r < 4; ++r) {
            const int m = m0 + mt * 16 + lh * 4 + r;
            float v = acc[mt][nt][r] + bia;
            if constexpr (EPI == 0) {
              g.outF[(size_t)m * g.ldo + n] = v;
            } else {  // EPI==1: sgate epilogue
              float sg = sigm(v + g.auxF[(size_t)(m & 63) * g.ldo + n]);
              float st = (float)g.auxBf[(size_t)m * g.ldo + n];
              g.outBf[(size_t)m * g.ldo + n] = (bf16)(sg * st);
            }
          }
        }
      }
    }
  }
}

// ---------------- small prep kernels ----------------
__global__ void f2b_k(const float* __restrict__ x, bf16* __restrict__ y, int n) {
  int i = blockIdx.x * 256 + threadIdx.x;
  if (i < n) y[i] = (bf16)x[i];
}

__global__ void init_k(unsigned* scal) {
  int i = threadIdx.x;
  if (i < 16) scal[i] = 0u;
}

__global__ void gather_k(const int* __restrict__ src, const float* __restrict__ emb,
                         bf16* __restrict__ embeds) {
  int i = blockIdx.x * 256 + threadIdx.x;  // over S*B*E
  int e = i & 255;
  int sb = i >> 8;
  int s = sb >> 6, b = sb & 63;
  int tok = src[b * cS + s];
  embeds[i] = (bf16)emb[(size_t)tok * cE + e];
}

__global__ void build_wp_k(const float* __restrict__ Wih_c, const float* __restrict__ Whh_c,
                           const float* __restrict__ bih_c, const float* __restrict__ bhh_c,
                           bf16* __restrict__ Wp, float* __restrict__ bp) {
  int i = blockIdx.x * 256 + threadIdx.x;  // over 2048*1280
  if (i >= cN4 * cKcat) return;
  int j = i / cKcat, c = i % cKcat;
  float v;
  if (j < 1024) v = (c < 768) ? Wih_c[(size_t)j * 768 + c] : Whh_c[(size_t)j * 512 + (c - 768)];
  else if (j < 1536) v = (c < 768) ? Wih_c[(size_t)j * 768 + c] : 0.f;
  else v = (c < 768) ? 0.f : Whh_c[(size_t)(j - 512) * 512 + (c - 768)];
  Wp[i] = (bf16)v;
  if (c == 0) {
    float bb;
    if (j < 1024) bb = bih_c[j] + bhh_c[j];
    else if (j < 1536) bb = bih_c[j];
    else bb = bhh_c[j - 512];
    bp[j] = bb;
  }
}

__global__ void concat_k(const float* __restrict__ hf, const float* __restrict__ hb,
                         bf16* __restrict__ hd_bf, float* __restrict__ hd_f) {
  int i = blockIdx.x * 256 + threadIdx.x;  // 64*512
  if (i >= cB * cH) return;
  int b = i >> 9, k = i & 511;
  float v = (k < 256) ? hf[b * 256 + k] : hb[b * 256 + (k - 256)];
  hd_bf[i] = (bf16)v;
  hd_f[i] = v;
}

// ---------------- encoder GRU v2: batch-split, zero inter-block sync ----------------
// 8 blocks = 2 dirs x 4 batch-chunks(16). 512 threads = 8 waves; wave w owns
// hidden units [w*32,(w+1)*32) for all 3 gates; full Whh register-resident
// (192 VGPR/lane). h: bf16 tile in LDS, fp32 carry in registers. gi prefetched
// one step ahead into LDS double-buffer via global_load_lds (drained by the
// compiler's vmcnt(0) at the publishing __syncthreads).
__global__ __launch_bounds__(512, 1) void enc_rnn_k(
    const bf16* __restrict__ WhhF, const bf16* __restrict__ WhhB,
    const float* __restrict__ giF, const float* __restrict__ giB,
    const float* __restrict__ bhhF, const float* __restrict__ bhhB,
    float* __restrict__ hfin, bf16* __restrict__ states) {
  const int blk = blockIdx.x;
  const int dir = blk >> 2;
  const int bc = blk & 3;  // batches [bc*16, bc*16+16)
  const bf16* Whh = dir ? WhhB : WhhF;
  const float* gi = dir ? giB : giF;
  const float* bhh = dir ? bhhB : bhhF;

  const int tid = threadIdx.x;
  const int lane = tid & 63, w = tid >> 6;
  const int lr = lane & 15, lh = lane >> 4;
  const int u0 = w * 32;

  // Whh fragments [gate*2+ut][kf]
  bf16x8 Bf[6][8];
  float bh[6];
#pragma unroll
  for (int gg = 0; gg < 3; ++gg)
#pragma unroll
    for (int ut = 0; ut < 2; ++ut) {
      int nbase = gg * 256 + u0 + ut * 16;
#pragma unroll
      for (int kf = 0; kf < 8; ++kf)
        Bf[gg * 2 + ut][kf] = *(const bf16x8*)(Whh + (size_t)(nbase + lr) * 256 + kf * 32 + lh * 8);
      bh[gg * 2 + ut] = bhh[nbase + lr];
    }

  __shared__ float gilds[2][16 * cG2];  // 96 KB double-buffered gi tile
  __shared__ bf16 hs[16][264];          // padded h tile

  auto prefetch = [&](int t2) {
    if (t2 >= cS) return;
    const int s2 = dir ? (cS - 1 - t2) : t2;
    const char* srcb = (const char*)(gi + ((size_t)s2 * cB + bc * 16) * cG2);
    char* dstb = (char*)&gilds[t2 & 1][0];
    const int off = w * 6 * 1024;  // wave w copies chunks [w*6, w*6+6) of 1 KB
#pragma unroll
    for (int c = 0; c < 6; ++c) {
      int o = off + c * 1024;
      gload_lds16(srcb + o + lane * 16, dstb + o);
    }
  };

  float hreg[2][4];
#pragma unroll
  for (int ut = 0; ut < 2; ++ut)
#pragma unroll
    for (int r = 0; r < 4; ++r) hreg[ut][r] = 0.f;

  prefetch(0);
  for (int i = tid; i < 16 * 256; i += 512) hs[i >> 8][i & 255] = (bf16)0.f;
  __syncthreads();  // drains prefetch(0) too

  for (int t = 0; t < cS; ++t) {
    prefetch(t + 1);

    f32x4 acc[6];
#pragma unroll
    for (int j = 0; j < 6; ++j)
#pragma unroll
      for (int r = 0; r < 4; ++r) acc[j][r] = 0.f;

#pragma unroll
    for (int kf = 0; kf < 8; ++kf) {
      bf16x8 av = *(const bf16x8*)(&hs[lr][kf * 32 + lh * 8]);
#pragma unroll
      for (int nt = 0; nt < 6; ++nt)
        acc[nt] = __builtin_amdgcn_mfma_f32_16x16x32_bf16(av, Bf[nt][kf], acc[nt], 0, 0, 0);
    }

    const int s_src = dir ? (cS - 1 - t) : t;
    const float* gl = &gilds[t & 1][0];
#pragma unroll
    for (int ut = 0; ut < 2; ++ut) {
      const int u = u0 + ut * 16 + lr;
#pragma unroll
      for (int r = 0; r < 4; ++r) {
        const int b = lh * 4 + r;
        float gir = gl[b * cG2 + u];
        float giz = gl[b * cG2 + 256 + u];
        float gin = gl[b * cG2 + 512 + u];
        float rr = sigm(gir + acc[ut][r] + bh[ut]);
        float zz = sigm(giz + acc[2 + ut][r] + bh[2 + ut]);
        float nn = tanh_f(gin + rr * (acc[4 + ut][r] + bh[4 + ut]));
        float hnew = (1.f - zz) * nn + zz * hreg[ut][r];
        hreg[ut][r] = hnew;
        states[((size_t)s_src * cB + bc * 16 + b) * cH + dir * 256 + u] = (bf16)hnew;
      }
    }

    __syncthreads();  // all hs reads done; also drains prefetch(t+1)
#pragma unroll
    for (int ut = 0; ut < 2; ++ut)
#pragma unroll
      for (int r = 0; r < 4; ++r)
        hs[lh * 4 + r][u0 + ut * 16 + lr] = (bf16)hreg[ut][r];
    __syncthreads();  // hs published
  }

  // final fp32 hidden -> hfin[dir][b][u]
#pragma unroll
  for (int ut = 0; ut < 2; ++ut)
#pragma unroll
    for (int r = 0; r < 4; ++r)
      hfin[((size_t)dir * cB + bc * 16 + lh * 4 + r) * cH2 + u0 + ut * 16 + lr] = hreg[ut][r];
}

// ---------------- decoder: attention + context + build xh ----------------
__global__ __launch_bounds__(256) void attn_k(
    const bf16* __restrict__ hin, const float* __restrict__ Wd, const float* __restrict__ bd,
    const float* __restrict__ Wo, const float* __restrict__ bo,
    const float* __restrict__ encproj, const bf16* __restrict__ statesg,
    const float* __restrict__ emb, const int* __restrict__ trg, int step,
    bf16* __restrict__ xh) {
  const int b = blockIdx.x, tid = threadIdx.x;
  const int lane = tid & 63, wid = tid >> 6;
  __shared__ float hsh[512];
  __shared__ float dsh[100];
  __shared__ float esh[400];
  __shared__ float red[16];

  for (int k = tid; k < 512; k += 256) hsh[k] = (float)hin[b * 512 + k];
  __syncthreads();
  if (tid < 100) {
    float a = bd[tid];
    const float* wr = Wd + (size_t)tid * 512;
    for (int k = 0; k < 512; ++k) a += hsh[k] * wr[k];
    dsh[tid] = a;
  }
  __syncthreads();

  const float bo0 = bo[0];
  float e0, e1 = -3.4e38f;
  {
    const float* ep = encproj + ((size_t)tid * cB + b) * cM;
    float a = bo0;
    for (int j = 0; j < 100; ++j) a += Wo[j] * tanh_f(dsh[j] + ep[j]);
    e0 = a;
  }
  if (tid < 144) {
    const float* ep = encproj + ((size_t)(tid + 256) * cB + b) * cM;
    float a = bo0;
    for (int j = 0; j < 100; ++j) a += Wo[j] * tanh_f(dsh[j] + ep[j]);
    e1 = a;
  }
  float mx = fmaxf(e0, e1);
#pragma unroll
  for (int msk = 1; msk < 64; msk <<= 1) mx = fmaxf(mx, __shfl_xor(mx, msk));
  if (lane == 0) red[wid] = mx;
  __syncthreads();
  mx = fmaxf(fmaxf(red[0], red[1]), fmaxf(red[2], red[3]));

  float a0 = __expf(e0 - mx);
  float a1 = (tid < 144) ? __expf(e1 - mx) : 0.f;
  esh[tid] = a0;
  if (tid < 144) esh[tid + 256] = a1;
  float sm = a0 + a1;
#pragma unroll
  for (int msk = 1; msk < 64; msk <<= 1) sm += __shfl_xor(sm, msk);
  if (lane == 0) red[8 + wid] = sm;
  __syncthreads();
  const float inv = 1.f / (red[8] + red[9] + red[10] + red[11]);

  for (int k = tid; k < 512; k += 256) {
    float a = 0.f;
    const bf16* sp = statesg + b * cH + k;
    for (int s = 0; s < cS; ++s) a += esh[s] * (float)sp[(size_t)s * (cB * cH)];
    xh[b * cKcat + k] = (bf16)(a * inv);
  }
  const int tok = trg[b * cT + step];
  xh[b * cKcat + 512 + tid] = (bf16)emb[(size_t)tok * cE + tid];
  for (int k = tid; k < 512; k += 256) xh[b * cKcat + 768 + k] = hin[b * 512 + k];
}

__global__ __launch_bounds__(256) void gru_gate_k(const float* __restrict__ g4,
                                                  const float* __restrict__ hin_f,
                                                  float* __restrict__ hout_f,
                                                  bf16* __restrict__ hout_bf) {
  int i = blockIdx.x * 256 + threadIdx.x;
  if (i >= cB * cH) return;
  int b = i >> 9, t = i & 511;
  const float* gb = g4 + (size_t)b * cN4;
  float r = sigm(gb[t]);
  float z = sigm(gb[512 + t]);
  float n = tanh_f(gb[1024 + t] + r * gb[1536 + t]);
  float h2 = (1.f - z) * n + z * hin_f[i];
  hout_f[i] = h2;
  hout_bf[i] = (bf16)h2;
}

// ---------------- per-step loss reduce (1 block, 1024 threads) ----------------
__global__ __launch_bounds__(1024) void loss_k(const float* __restrict__ partials,
                                               const bf16* __restrict__ h2,
                                               const float* __restrict__ Wv,
                                               const float* __restrict__ bv,
                                               const int* __restrict__ trg, int step,
                                               float* __restrict__ accum,
                                               float* __restrict__ out) {
  const int tid = threadIdx.x;
  const int row = tid >> 4, j = tid & 15;
  float mx = -3.4e38f, sm = 0.f;
  for (int p = j; p < cNTV; p += 16) {
    const float* pp = partials + ((size_t)p * 64 + row) * 2;
    float m2 = pp[0], s2 = pp[1];
    if (m2 > mx) { sm = sm * __expf(mx - m2) + s2; mx = m2; }
    else sm += s2 * __expf(m2 - mx);
  }
#pragma unroll
  for (int msk = 1; msk < 16; msk <<= 1) {
    float om = __shfl_xor(mx, msk), os = __shfl_xor(sm, msk);
    if (om > mx) { sm = sm * __expf(mx - om) + os; mx = om; }
    else sm += os * __expf(om - mx);
  }
  const int tok = trg[row * cT + step];
  float dot = 0.f;
  const float* wr = Wv + (size_t)tok * cH;
  const bf16* hr = h2 + row * cH;
  for (int k = j * 32; k < j * 32 + 32; ++k) dot += (float)hr[k] * wr[k];
#pragma unroll
  for (int msk = 1; msk < 16; msk <<= 1) dot += __shfl_xor(dot, msk);

  __shared__ float wnll[64];
  __shared__ float wsh[64];
  if (j == 0) {
    float lse = mx + __logf(sm);
    float logit = dot + bv[tok];
    float nll = lse - logit;
    float wgt = (tok != cEOS) ? 1.f : 0.f;
    wnll[row] = wgt * nll;
    wsh[row] = wgt;
  }
  __syncthreads();
  if (tid == 0) {
    float a = 0.f, d = 0.f;
    for (int i = 0; i < 64; ++i) { a += wnll[i]; d += wsh[i]; }
    float sl = a / d;
    float tot = *accum + sl * (1.f / (float)cB);
    *accum = tot;
    if (step == cT - 2) out[0] = tot;
  }
}

// ---------------- host ----------------
extern "C" void kernel_launch(void* const* d_in, const int* in_sizes, int n_in,
                              void* d_out, int out_size, void* d_ws, size_t ws_size,
                              hipStream_t stream) {
  (void)in_sizes; (void)n_in; (void)out_size; (void)ws_size;
  const int* src = (const int*)d_in[0];
  const int* trg = (const int*)d_in[1];
  const float* emb = (const float*)d_in[2];
  const float* Wih_f = (const float*)d_in[3];
  const float* Whh_f = (const float*)d_in[4];
  const float* bih_f = (const float*)d_in[5];
  const float* bhh_f = (const float*)d_in[6];
  const float* Wih_b = (const float*)d_in[7];
  const float* Whh_b = (const float*)d_in[8];
  const float* bih_b = (const float*)d_in[9];
  const float* bhh_b = (const float*)d_in[10];
  const float* W1 = (const float*)d_in[11];
  const float* b1 = (const float*)d_in[12];
  const float* W2 = (const float*)d_in[13];
  const float* b2 = (const float*)d_in[14];
  const float* Wd = (const float*)d_in[15];
  const float* bd = (const float*)d_in[16];
  const float* We = (const float*)d_in[17];
  const float* be = (const float*)d_in[18];
  const float* Wo = (const float*)d_in[19];
  const float* bo = (const float*)d_in[20];
  const float* Wih_c = (const float*)d_in[21];
  const float* Whh_c = (const float*)d_in[22];
  const float* bih_c = (const float*)d_in[23];
  const float* bhh_c = (const float*)d_in[24];
  const float* Wv = (const float*)d_in[25];
  const float* bv = (const float*)d_in[26];
  float* out = (float*)d_out;

  char* ws = (char*)d_ws;
  size_t off = 0;
  auto carve = [&](size_t bytes) -> void* {
    void* p = ws + off;
    off += (bytes + 255) & ~(size_t)255;
    return p;
  };
  bf16* Wihf_b = (bf16*)carve((size_t)cG2 * cE * 2);
  bf16* Whhf_b = (bf16*)carve((size_t)cG2 * cH2 * 2);
  bf16* Wihb_b = (bf16*)carve((size_t)cG2 * cE * 2);
  bf16* Whhb_b = (bf16*)carve((size_t)cG2 * cH2 * 2);
  bf16* W1_b = (bf16*)carve((size_t)cH * cH * 2);
  bf16* W2_b = (bf16*)carve((size_t)cH * cH * 2);
  bf16* We_b = (bf16*)carve((size_t)cM * cH * 2);
  bf16* Wv_b = (bf16*)carve((size_t)cV * cH * 2);
  bf16* Wp_b = (bf16*)carve((size_t)cN4 * cKcat * 2);
  float* bp = (float*)carve((size_t)cN4 * 4);
  bf16* embeds = (bf16*)carve((size_t)cSB * cE * 2);
  float* gi_f = (float*)carve((size_t)cSB * cG2 * 4);
  float* gi_b = (float*)carve((size_t)cSB * cG2 * 4);
  bf16* states = (bf16*)carve((size_t)cSB * cH * 2);
  bf16* statesg = (bf16*)carve((size_t)cSB * cH * 2);
  float* hfin = (float*)carve((size_t)2 * cB * cH2 * 4);
  bf16* hdec0_bf = (bf16*)carve((size_t)cB * cH * 2);
  float* hdec0_f = (float*)carve((size_t)cB * cH * 4);
  bf16* hping_bf0 = (bf16*)carve((size_t)cB * cH * 2);
  bf16* hping_bf1 = (bf16*)carve((size_t)cB * cH * 2);
  float* hping_f0 = (float*)carve((size_t)cB * cH * 4);
  float* hping_f1 = (float*)carve((size_t)cB * cH * 4);
  float* hw2 = (float*)carve((size_t)cB * cH * 4);
  float* encproj = (float*)carve((size_t)cSB * cM * 4);
  bf16* xh = (bf16*)carve((size_t)cB * cKcat * 2);
  float* g4 = (float*)carve((size_t)cB * cN4 * 4);
  float* partials = (float*)carve((size_t)cNTV * 64 * 2 * 4);
  unsigned* scal = (unsigned*)carve(64);
  float* accum = (float*)(scal + 8);

  auto cvt = [&](const float* x, bf16* y, int n) {
    f2b_k<<<dim3((n + 255) / 256), dim3(256), 0, stream>>>(x, y, n);
  };
  auto gemm0 = [&](const bf16* A, const bf16* Bm, const float* bias, float* outF,
                   int M, int N, int K, int ldo) {
    GArgs ga{A, Bm, bias, outF, nullptr, nullptr, nullptr, nullptr, M, N, K, ldo};
    int waves = (M / 64) * ((N + 63) / 64);
    gemm64_k<0><<<dim3((waves + 3) / 4), dim3(256), 0, stream>>>(ga);
  };

  // init + weight prep
  init_k<<<dim3(1), dim3(64), 0, stream>>>(scal);
  cvt(Wih_f, Wihf_b, cG2 * cE);
  cvt(Whh_f, Whhf_b, cG2 * cH2);
  cvt(Wih_b, Wihb_b, cG2 * cE);
  cvt(Whh_b, Whhb_b, cG2 * cH2);
  cvt(W1, W1_b, cH * cH);
  cvt(W2, W2_b, cH * cH);
  cvt(We, We_b, cM * cH);
  cvt(Wv, Wv_b, cV * cH);
  build_wp_k<<<dim3((cN4 * cKcat + 255) / 256), dim3(256), 0, stream>>>(Wih_c, Whh_c, bih_c, bhh_c, Wp_b, bp);

  // encoder
  gather_k<<<dim3(cSB * cE / 256), dim3(256), 0, stream>>>(src, emb, embeds);
  gemm0(embeds, Wihf_b, bih_f, gi_f, cSB, cG2, cE, cG2);
  gemm0(embeds, Wihb_b, bih_b, gi_b, cSB, cG2, cE, cG2);
  enc_rnn_k<<<dim3(8), dim3(512), 0, stream>>>(Whhf_b, Whhb_b, gi_f, gi_b, bhh_f, bhh_b,
                                               hfin, states);
  concat_k<<<dim3((cB * cH + 255) / 256), dim3(256), 0, stream>>>(
      hfin, hfin + (size_t)cB * cH2, hdec0_bf, hdec0_f);
  gemm0(hdec0_bf, W2_b, b2, hw2, cB, cH, cH, cH);
  {  // sgate: statesg = sigmoid(states@W1^T + b1 + hw2) * states
    GArgs ga{states, W1_b, b1, nullptr, statesg, hw2, states, nullptr, cSB, cH, cH, cH};
    int waves = (cSB / 64) * (cH / 64);
    gemm64_k<1><<<dim3((waves + 3) / 4), dim3(256), 0, stream>>>(ga);
  }
  gemm0(statesg, We_b, be, encproj, cSB, cM, cH, cM);

  // decoder
  for (int t = 0; t < cT - 1; ++t) {
    const bf16* hin_bf = (t == 0) ? hdec0_bf : ((t & 1) ? hping_bf0 : hping_bf1);
    const float* hin_f = (t == 0) ? hdec0_f : ((t & 1) ? hping_f0 : hping_f1);
    bf16* hout_bf = (t & 1) ? hping_bf1 : hping_bf0;
    float* hout_f = (t & 1) ? hping_f1 : hping_f0;

    attn_k<<<dim3(cB), dim3(256), 0, stream>>>(hin_bf, Wd, bd, Wo, bo, encproj, statesg,
                                               emb, trg, t, xh);
    gemm0(xh, Wp_b, bp, g4, cB, cN4, cKcat, cN4);
    gru_gate_k<<<dim3((cB * cH + 255) / 256), dim3(256), 0, stream>>>(g4, hin_f, hout_f, hout_bf);
    {  // logits partials
      GArgs ga{hout_bf, Wv_b, bv, nullptr, nullptr, nullptr, nullptr, partials, cB, cV, cH, 0};
      int waves = cNTV;  // 782
      gemm64_k<3><<<dim3((waves + 3) / 4), dim3(256), 0, stream>>>(ga);
    }
    loss_k<<<dim3(1), dim3(1024), 0, stream>>>(partials, hout_bf, Wv, bv, trg, t, accum, out);
  }
}

// Round 3
// 5597.650 us; speedup vs baseline: 1.6806x; 1.0158x over previous
//
#include <hip/hip_runtime.h>

typedef __bf16 bf16;
typedef bf16 bf16x8 __attribute__((ext_vector_type(8)));
typedef float f32x4 __attribute__((ext_vector_type(4)));

#define DEVFN __device__ __forceinline__

constexpr int cV = 50000, cE = 256, cH = 512, cM = 100, cH2 = 256;
constexpr int cB = 64, cS = 400, cT = 25, cEOS = 2;
constexpr int cSB = cS * cB;          // 25600
constexpr int cG2 = 3 * cH2;          // 768
constexpr int cGP = 772;              // gi LDS row pad (772%32=4 -> 2-way, free)
constexpr int cKcat = 1280;           // [c(512) | wemb(256) | h(512)]
constexpr int cN4 = 2048;             // r,z,inn,hn rows
constexpr int cNTV = (cV + 63) / 64;  // 782

struct GArgs {
  const bf16* A; const bf16* Bw; const float* bias;
  float* outF; bf16* outBf;
  const float* auxF; const bf16* auxBf;
  float* partials;
  int M, N, K, ldo;
};

DEVFN float sigm(float x) { return 1.f / (1.f + __expf(-x)); }
DEVFN float tanh_f(float x) {
  float e2 = __expf(2.f * x);
  return 1.f - 2.f / (e2 + 1.f);
}

DEVFN void gload_lds16(const void* g, void* l) {
  __builtin_amdgcn_global_load_lds(
      (const __attribute__((address_space(1))) void*)g,
      (__attribute__((address_space(3))) void*)l, 16, 0, 0);
}

// ---------------- generic 64x64-per-wave MFMA GEMM: C = A(MxK) * B(NxK)^T ----------------
template <int EPI>
__global__ __launch_bounds__(256) void gemm64_k(GArgs g) {
  const int tid = threadIdx.x;
  const int w = blockIdx.x * 4 + (tid >> 6);
  const int tM = g.M >> 6;
  const int tN = (g.N + 63) >> 6;
  if (w >= tM * tN) return;
  const int im = w % tM, in = w / tM;
  const int m0 = im << 6, n0 = in << 6;
  const int lane = tid & 63, lr = lane & 15, lh = lane >> 4;

  f32x4 acc[4][4];
#pragma unroll
  for (int i = 0; i < 4; ++i)
#pragma unroll
    for (int j = 0; j < 4; ++j)
#pragma unroll
      for (int r = 0; r < 4; ++r) acc[i][j][r] = 0.f;

  bf16x8 bz;
#pragma unroll
  for (int q = 0; q < 8; ++q) bz[q] = (bf16)0.f;

  const int K = g.K;
  for (int k0 = 0; k0 < K; k0 += 32) {
    bf16x8 av[4], bw[4];
#pragma unroll
    for (int mt = 0; mt < 4; ++mt)
      av[mt] = *(const bf16x8*)(g.A + (size_t)(m0 + mt * 16 + lr) * K + k0 + lh * 8);
#pragma unroll
    for (int nt = 0; nt < 4; ++nt) {
      int row = n0 + nt * 16 + lr;
      bw[nt] = (row < g.N) ? *(const bf16x8*)(g.Bw + (size_t)row * K + k0 + lh * 8) : bz;
    }
#pragma unroll
    for (int mt = 0; mt < 4; ++mt)
#pragma unroll
      for (int nt = 0; nt < 4; ++nt)
        acc[mt][nt] = __builtin_amdgcn_mfma_f32_16x16x32_bf16(av[mt], bw[nt], acc[mt][nt], 0, 0, 0);
  }

  if constexpr (EPI == 3) {
    // per-row (mx, sumexp) partials over this 64-col tile
#pragma unroll
    for (int mt = 0; mt < 4; ++mt) {
#pragma unroll
      for (int r = 0; r < 4; ++r) {
        const int m = m0 + mt * 16 + lh * 4 + r;
        float vv[4];
        float mx = -3.4e38f;
#pragma unroll
        for (int nt = 0; nt < 4; ++nt) {
          int n = n0 + nt * 16 + lr;
          float v = (n < g.N) ? (acc[mt][nt][r] + g.bias[n]) : -3.4e38f;
          vv[nt] = v;
          mx = fmaxf(mx, v);
        }
#pragma unroll
        for (int msk = 1; msk < 16; msk <<= 1) mx = fmaxf(mx, __shfl_xor(mx, msk));
        float sm = 0.f;
#pragma unroll
        for (int nt = 0; nt < 4; ++nt) {
          int n = n0 + nt * 16 + lr;
          if (n < g.N) sm += __expf(vv[nt] - mx);
        }
#pragma unroll
        for (int msk = 1; msk < 16; msk <<= 1) sm += __shfl_xor(sm, msk);
        if (lr == 0) {
          float* p = g.partials + ((size_t)in * 64 + m) * 2;
          p[0] = mx;
          p[1] = sm;
        }
      }
    }
  } else {
#pragma unroll
    for (int mt = 0; mt < 4; ++mt) {
#pragma unroll
      for (int nt = 0; nt < 4; ++nt) {
        const int n = n0 + nt * 16 + lr;
        if (n < g.N) {
          const float bia = g.bias[n];
#pragma unroll
          for (int r = 0; r < 4; ++r) {
            const int m = m0 + mt * 16 + lh * 4 + r;
            float v = acc[mt][nt][r] + bia;
            if constexpr (EPI == 0) {
              g.outF[(size_t)m * g.ldo + n] = v;
            } else {  // EPI==1: sgate epilogue
              float sg = sigm(v + g.auxF[(size_t)(m & 63) * g.ldo + n]);
              float st = (float)g.auxBf[(size_t)m * g.ldo + n];
              g.outBf[(size_t)m * g.ldo + n] = (bf16)(sg * st);
            }
          }
        }
      }
    }
  }
}

// ---------------- small prep kernels ----------------
__global__ void f2b_k(const float* __restrict__ x, bf16* __restrict__ y, int n) {
  int i = blockIdx.x * 256 + threadIdx.x;
  if (i < n) y[i] = (bf16)x[i];
}

__global__ void init_k(unsigned* scal) {
  int i = threadIdx.x;
  if (i < 16) scal[i] = 0u;
}

__global__ void gather_k(const int* __restrict__ src, const float* __restrict__ emb,
                         bf16* __restrict__ embeds) {
  int i = blockIdx.x * 256 + threadIdx.x;  // over S*B*E
  int e = i & 255;
  int sb = i >> 8;
  int s = sb >> 6, b = sb & 63;
  int tok = src[b * cS + s];
  embeds[i] = (bf16)emb[(size_t)tok * cE + e];
}

__global__ void build_wp_k(const float* __restrict__ Wih_c, const float* __restrict__ Whh_c,
                           const float* __restrict__ bih_c, const float* __restrict__ bhh_c,
                           bf16* __restrict__ Wp, float* __restrict__ bp) {
  int i = blockIdx.x * 256 + threadIdx.x;  // over 2048*1280
  if (i >= cN4 * cKcat) return;
  int j = i / cKcat, c = i % cKcat;
  float v;
  if (j < 1024) v = (c < 768) ? Wih_c[(size_t)j * 768 + c] : Whh_c[(size_t)j * 512 + (c - 768)];
  else if (j < 1536) v = (c < 768) ? Wih_c[(size_t)j * 768 + c] : 0.f;
  else v = (c < 768) ? 0.f : Whh_c[(size_t)(j - 512) * 512 + (c - 768)];
  Wp[i] = (bf16)v;
  if (c == 0) {
    float bb;
    if (j < 1024) bb = bih_c[j] + bhh_c[j];
    else if (j < 1536) bb = bih_c[j];
    else bb = bhh_c[j - 512];
    bp[j] = bb;
  }
}

__global__ void concat_k(const float* __restrict__ hf, const float* __restrict__ hb,
                         bf16* __restrict__ hd_bf, float* __restrict__ hd_f) {
  int i = blockIdx.x * 256 + threadIdx.x;  // 64*512
  if (i >= cB * cH) return;
  int b = i >> 9, k = i & 511;
  float v = (k < 256) ? hf[b * 256 + k] : hb[b * 256 + (k - 256)];
  hd_bf[i] = (bf16)v;
  hd_f[i] = v;
}

// ---------------- encoder GRU v3: single barrier/step, stores off critical path ----------------
// 8 blocks = 2 dirs x 4 batch-chunks(16). 512 threads = 8 waves; wave w owns
// hidden units [w*32,(w+1)*32) for all 3 gates; full Whh register/AGPR-resident.
// hs double-buffered -> ONE __syncthreads per step (waves desync within step,
// gate VALU of early waves overlaps MFMA of late waves). states written
// coalesced AFTER the barrier (a full step of slack before the next vmcnt
// drain). gi prefetched 1 step ahead via global_load_lds into padded rows.
__global__ __launch_bounds__(512, 1) void enc_rnn_k(
    const bf16* __restrict__ WhhF, const bf16* __restrict__ WhhB,
    const float* __restrict__ giF, const float* __restrict__ giB,
    const float* __restrict__ bhhF, const float* __restrict__ bhhB,
    float* __restrict__ hfin, bf16* __restrict__ states) {
  const int blk = blockIdx.x;
  const int dir = blk >> 2;
  const int bc = blk & 3;  // batches [bc*16, bc*16+16)
  const bf16* Whh = dir ? WhhB : WhhF;
  const float* gi = dir ? giB : giF;
  const float* bhh = dir ? bhhB : bhhF;

  const int tid = threadIdx.x;
  const int lane = tid & 63, w = tid >> 6;
  const int lr = lane & 15, lh = lane >> 4;
  const int u0 = w * 32;

  // Whh fragments [gate*2+ut][kf]
  bf16x8 Bf[6][8];
  float bh[6];
#pragma unroll
  for (int gg = 0; gg < 3; ++gg)
#pragma unroll
    for (int ut = 0; ut < 2; ++ut) {
      int nbase = gg * 256 + u0 + ut * 16;
#pragma unroll
      for (int kf = 0; kf < 8; ++kf)
        Bf[gg * 2 + ut][kf] = *(const bf16x8*)(Whh + (size_t)(nbase + lr) * 256 + kf * 32 + lh * 8);
      bh[gg * 2 + ut] = bhh[nbase + lr];
    }

  __shared__ float gilds[2][16][cGP];  // 98.8 KB double-buffered gi tile, padded rows
  __shared__ bf16 hs[2][16][264];      // 16.9 KB double-buffered h tile

  auto prefetch = [&](int t2) {
    if (t2 >= cS) return;
    const int s2 = dir ? (cS - 1 - t2) : t2;
    const int buf = t2 & 1;
    // wave w: batch rows 2w, 2w+1; 3 chunks of 1KB each (row = 768 f32 = 3KB)
#pragma unroll
    for (int rr2 = 0; rr2 < 2; ++rr2) {
      const int row = w * 2 + rr2;
      const char* srcb = (const char*)(gi + ((size_t)s2 * cB + bc * 16 + row) * cG2);
      char* dstb = (char*)&gilds[buf][row][0];
#pragma unroll
      for (int c = 0; c < 3; ++c)
        gload_lds16(srcb + c * 1024 + lane * 16, dstb + c * 1024);
    }
  };

  float hreg[2][4];
#pragma unroll
  for (int ut = 0; ut < 2; ++ut)
#pragma unroll
    for (int r = 0; r < 4; ++r) hreg[ut][r] = 0.f;

  prefetch(0);
  for (int i = tid; i < 16 * 264; i += 512) ((bf16*)hs[0])[i] = (bf16)0.f;
  __syncthreads();  // drains prefetch(0) too

  for (int t = 0; t < cS; ++t) {
    const int buf = t & 1, nbuf = buf ^ 1;
    prefetch(t + 1);

    // hs fragment reads first (MFMA's lgkm wait shouldn't trail the gi reads)
    bf16x8 av[8];
#pragma unroll
    for (int kf = 0; kf < 8; ++kf)
      av[kf] = *(const bf16x8*)(&hs[buf][lr][kf * 32 + lh * 8]);

    // gi -> registers (independent of MFMA; latency hides under it)
    float gir[2][4], giz[2][4], gin[2][4];
#pragma unroll
    for (int ut = 0; ut < 2; ++ut) {
      const int u = u0 + ut * 16 + lr;
#pragma unroll
      for (int r = 0; r < 4; ++r) {
        const int b = lh * 4 + r;
        gir[ut][r] = gilds[buf][b][u];
        giz[ut][r] = gilds[buf][b][256 + u];
        gin[ut][r] = gilds[buf][b][512 + u];
      }
    }

    f32x4 acc[6];
#pragma unroll
    for (int j = 0; j < 6; ++j)
#pragma unroll
      for (int r = 0; r < 4; ++r) acc[j][r] = 0.f;

#pragma unroll
    for (int kf = 0; kf < 8; ++kf)
#pragma unroll
      for (int nt = 0; nt < 6; ++nt)
        acc[nt] = __builtin_amdgcn_mfma_f32_16x16x32_bf16(av[kf], Bf[nt][kf], acc[nt], 0, 0, 0);

#pragma unroll
    for (int ut = 0; ut < 2; ++ut) {
      const int u = u0 + ut * 16 + lr;
#pragma unroll
      for (int r = 0; r < 4; ++r) {
        const int b = lh * 4 + r;
        float rr = sigm(gir[ut][r] + acc[ut][r] + bh[ut]);
        float zz = sigm(giz[ut][r] + acc[2 + ut][r] + bh[2 + ut]);
        float nn = tanh_f(gin[ut][r] + rr * (acc[4 + ut][r] + bh[4 + ut]));
        float hnew = (1.f - zz) * nn + zz * hreg[ut][r];
        hreg[ut][r] = hnew;
        hs[nbuf][b][u] = (bf16)hnew;
      }
    }

    __syncthreads();  // hs[nbuf] published; drains prefetch(t+1) + last step's states store

    // coalesced states store (off the critical path: retires during step t+1)
    {
      const int s_src = dir ? (cS - 1 - t) : t;
      const int row = tid >> 5, c8 = tid & 31;
      bf16x8 v = *(const bf16x8*)(&hs[nbuf][row][c8 * 8]);
      *(bf16x8*)(states + ((size_t)s_src * cB + bc * 16 + row) * cH + dir * 256 + c8 * 8) = v;
    }
  }

  // final fp32 hidden -> hfin[dir][b][u]
#pragma unroll
  for (int ut = 0; ut < 2; ++ut)
#pragma unroll
    for (int r = 0; r < 4; ++r)
      hfin[((size_t)dir * cB + bc * 16 + lh * 4 + r) * cH2 + u0 + ut * 16 + lr] = hreg[ut][r];
}

// ---------------- decoder: attention + context + build xh ----------------
__global__ __launch_bounds__(256) void attn_k(
    const bf16* __restrict__ hin, const float* __restrict__ Wd, const float* __restrict__ bd,
    const float* __restrict__ Wo, const float* __restrict__ bo,
    const float* __restrict__ encproj, const bf16* __restrict__ statesg,
    const float* __restrict__ emb, const int* __restrict__ trg, int step,
    bf16* __restrict__ xh) {
  const int b = blockIdx.x, tid = threadIdx.x;
  const int lane = tid & 63, wid = tid >> 6;
  __shared__ float hsh[512];
  __shared__ float dsh[100];
  __shared__ float esh[400];
  __shared__ float red[16];

  for (int k = tid; k < 512; k += 256) hsh[k] = (float)hin[b * 512 + k];
  __syncthreads();
  if (tid < 100) {
    float a = bd[tid];
    const float* wr = Wd + (size_t)tid * 512;
    for (int k = 0; k < 512; ++k) a += hsh[k] * wr[k];
    dsh[tid] = a;
  }
  __syncthreads();

  const float bo0 = bo[0];
  float e0, e1 = -3.4e38f;
  {
    const float* ep = encproj + ((size_t)tid * cB + b) * cM;
    float a = bo0;
    for (int j = 0; j < 100; ++j) a += Wo[j] * tanh_f(dsh[j] + ep[j]);
    e0 = a;
  }
  if (tid < 144) {
    const float* ep = encproj + ((size_t)(tid + 256) * cB + b) * cM;
    float a = bo0;
    for (int j = 0; j < 100; ++j) a += Wo[j] * tanh_f(dsh[j] + ep[j]);
    e1 = a;
  }
  float mx = fmaxf(e0, e1);
#pragma unroll
  for (int msk = 1; msk < 64; msk <<= 1) mx = fmaxf(mx, __shfl_xor(mx, msk));
  if (lane == 0) red[wid] = mx;
  __syncthreads();
  mx = fmaxf(fmaxf(red[0], red[1]), fmaxf(red[2], red[3]));

  float a0 = __expf(e0 - mx);
  float a1 = (tid < 144) ? __expf(e1 - mx) : 0.f;
  esh[tid] = a0;
  if (tid < 144) esh[tid + 256] = a1;
  float sm = a0 + a1;
#pragma unroll
  for (int msk = 1; msk < 64; msk <<= 1) sm += __shfl_xor(sm, msk);
  if (lane == 0) red[8 + wid] = sm;
  __syncthreads();
  const float inv = 1.f / (red[8] + red[9] + red[10] + red[11]);

  for (int k = tid; k < 512; k += 256) {
    float a = 0.f;
    const bf16* sp = statesg + b * cH + k;
    for (int s = 0; s < cS; ++s) a += esh[s] * (float)sp[(size_t)s * (cB * cH)];
    xh[b * cKcat + k] = (bf16)(a * inv);
  }
  const int tok = trg[b * cT + step];
  xh[b * cKcat + 512 + tid] = (bf16)emb[(size_t)tok * cE + tid];
  for (int k = tid; k < 512; k += 256) xh[b * cKcat + 768 + k] = hin[b * 512 + k];
}

__global__ __launch_bounds__(256) void gru_gate_k(const float* __restrict__ g4,
                                                  const float* __restrict__ hin_f,
                                                  float* __restrict__ hout_f,
                                                  bf16* __restrict__ hout_bf) {
  int i = blockIdx.x * 256 + threadIdx.x;
  if (i >= cB * cH) return;
  int b = i >> 9, t = i & 511;
  const float* gb = g4 + (size_t)b * cN4;
  float r = sigm(gb[t]);
  float z = sigm(gb[512 + t]);
  float n = tanh_f(gb[1024 + t] + r * gb[1536 + t]);
  float h2 = (1.f - z) * n + z * hin_f[i];
  hout_f[i] = h2;
  hout_bf[i] = (bf16)h2;
}

// ---------------- per-step loss reduce (1 block, 1024 threads) ----------------
__global__ __launch_bounds__(1024) void loss_k(const float* __restrict__ partials,
                                               const bf16* __restrict__ h2,
                                               const float* __restrict__ Wv,
                                               const float* __restrict__ bv,
                                               const int* __restrict__ trg, int step,
                                               float* __restrict__ accum,
                                               float* __restrict__ out) {
  const int tid = threadIdx.x;
  const int row = tid >> 4, j = tid & 15;
  float mx = -3.4e38f, sm = 0.f;
  for (int p = j; p < cNTV; p += 16) {
    const float* pp = partials + ((size_t)p * 64 + row) * 2;
    float m2 = pp[0], s2 = pp[1];
    if (m2 > mx) { sm = sm * __expf(mx - m2) + s2; mx = m2; }
    else sm += s2 * __expf(m2 - mx);
  }
#pragma unroll
  for (int msk = 1; msk < 16; msk <<= 1) {
    float om = __shfl_xor(mx, msk), os = __shfl_xor(sm, msk);
    if (om > mx) { sm = sm * __expf(mx - om) + os; mx = om; }
    else sm += os * __expf(om - mx);
  }
  const int tok = trg[row * cT + step];
  float dot = 0.f;
  const float* wr = Wv + (size_t)tok * cH;
  const bf16* hr = h2 + row * cH;
  for (int k = j * 32; k < j * 32 + 32; ++k) dot += (float)hr[k] * wr[k];
#pragma unroll
  for (int msk = 1; msk < 16; msk <<= 1) dot += __shfl_xor(dot, msk);

  __shared__ float wnll[64];
  __shared__ float wsh[64];
  if (j == 0) {
    float lse = mx + __logf(sm);
    float logit = dot + bv[tok];
    float nll = lse - logit;
    float wgt = (tok != cEOS) ? 1.f : 0.f;
    wnll[row] = wgt * nll;
    wsh[row] = wgt;
  }
  __syncthreads();
  if (tid == 0) {
    float a = 0.f, d = 0.f;
    for (int i = 0; i < 64; ++i) { a += wnll[i]; d += wsh[i]; }
    float sl = a / d;
    float tot = *accum + sl * (1.f / (float)cB);
    *accum = tot;
    if (step == cT - 2) out[0] = tot;
  }
}

// ---------------- host ----------------
extern "C" void kernel_launch(void* const* d_in, const int* in_sizes, int n_in,
                              void* d_out, int out_size, void* d_ws, size_t ws_size,
                              hipStream_t stream) {
  (void)in_sizes; (void)n_in; (void)out_size; (void)ws_size;
  const int* src = (const int*)d_in[0];
  const int* trg = (const int*)d_in[1];
  const float* emb = (const float*)d_in[2];
  const float* Wih_f = (const float*)d_in[3];
  const float* Whh_f = (const float*)d_in[4];
  const float* bih_f = (const float*)d_in[5];
  const float* bhh_f = (const float*)d_in[6];
  const float* Wih_b = (const float*)d_in[7];
  const float* Whh_b = (const float*)d_in[8];
  const float* bih_b = (const float*)d_in[9];
  const float* bhh_b = (const float*)d_in[10];
  const float* W1 = (const float*)d_in[11];
  const float* b1 = (const float*)d_in[12];
  const float* W2 = (const float*)d_in[13];
  const float* b2 = (const float*)d_in[14];
  const float* Wd = (const float*)d_in[15];
  const float* bd = (const float*)d_in[16];
  const float* We = (const float*)d_in[17];
  const float* be = (const float*)d_in[18];
  const float* Wo = (const float*)d_in[19];
  const float* bo = (const float*)d_in[20];
  const float* Wih_c = (const float*)d_in[21];
  const float* Whh_c = (const float*)d_in[22];
  const float* bih_c = (const float*)d_in[23];
  const float* bhh_c = (const float*)d_in[24];
  const float* Wv = (const float*)d_in[25];
  const float* bv = (const float*)d_in[26];
  float* out = (float*)d_out;

  char* ws = (char*)d_ws;
  size_t off = 0;
  auto carve = [&](size_t bytes) -> void* {
    void* p = ws + off;
    off += (bytes + 255) & ~(size_t)255;
    return p;
  };
  bf16* Wihf_b = (bf16*)carve((size_t)cG2 * cE * 2);
  bf16* Whhf_b = (bf16*)carve((size_t)cG2 * cH2 * 2);
  bf16* Wihb_b = (bf16*)carve((size_t)cG2 * cE * 2);
  bf16* Whhb_b = (bf16*)carve((size_t)cG2 * cH2 * 2);
  bf16* W1_b = (bf16*)carve((size_t)cH * cH * 2);
  bf16* W2_b = (bf16*)carve((size_t)cH * cH * 2);
  bf16* We_b = (bf16*)carve((size_t)cM * cH * 2);
  bf16* Wv_b = (bf16*)carve((size_t)cV * cH * 2);
  bf16* Wp_b = (bf16*)carve((size_t)cN4 * cKcat * 2);
  float* bp = (float*)carve((size_t)cN4 * 4);
  bf16* embeds = (bf16*)carve((size_t)cSB * cE * 2);
  float* gi_f = (float*)carve((size_t)cSB * cG2 * 4);
  float* gi_b = (float*)carve((size_t)cSB * cG2 * 4);
  bf16* states = (bf16*)carve((size_t)cSB * cH * 2);
  bf16* statesg = (bf16*)carve((size_t)cSB * cH * 2);
  float* hfin = (float*)carve((size_t)2 * cB * cH2 * 4);
  bf16* hdec0_bf = (bf16*)carve((size_t)cB * cH * 2);
  float* hdec0_f = (float*)carve((size_t)cB * cH * 4);
  bf16* hping_bf0 = (bf16*)carve((size_t)cB * cH * 2);
  bf16* hping_bf1 = (bf16*)carve((size_t)cB * cH * 2);
  float* hping_f0 = (float*)carve((size_t)cB * cH * 4);
  float* hping_f1 = (float*)carve((size_t)cB * cH * 4);
  float* hw2 = (float*)carve((size_t)cB * cH * 4);
  float* encproj = (float*)carve((size_t)cSB * cM * 4);
  bf16* xh = (bf16*)carve((size_t)cB * cKcat * 2);
  float* g4 = (float*)carve((size_t)cB * cN4 * 4);
  float* partials = (float*)carve((size_t)cNTV * 64 * 2 * 4);
  unsigned* scal = (unsigned*)carve(64);
  float* accum = (float*)(scal + 8);

  auto cvt = [&](const float* x, bf16* y, int n) {
    f2b_k<<<dim3((n + 255) / 256), dim3(256), 0, stream>>>(x, y, n);
  };
  auto gemm0 = [&](const bf16* A, const bf16* Bm, const float* bias, float* outF,
                   int M, int N, int K, int ldo) {
    GArgs ga{A, Bm, bias, outF, nullptr, nullptr, nullptr, nullptr, M, N, K, ldo};
    int waves = (M / 64) * ((N + 63) / 64);
    gemm64_k<0><<<dim3((waves + 3) / 4), dim3(256), 0, stream>>>(ga);
  };

  // init + weight prep
  init_k<<<dim3(1), dim3(64), 0, stream>>>(scal);
  cvt(Wih_f, Wihf_b, cG2 * cE);
  cvt(Whh_f, Whhf_b, cG2 * cH2);
  cvt(Wih_b, Wihb_b, cG2 * cE);
  cvt(Whh_b, Whhb_b, cG2 * cH2);
  cvt(W1, W1_b, cH * cH);
  cvt(W2, W2_b, cH * cH);
  cvt(We, We_b, cM * cH);
  cvt(Wv, Wv_b, cV * cH);
  build_wp_k<<<dim3((cN4 * cKcat + 255) / 256), dim3(256), 0, stream>>>(Wih_c, Whh_c, bih_c, bhh_c, Wp_b, bp);

  // encoder
  gather_k<<<dim3(cSB * cE / 256), dim3(256), 0, stream>>>(src, emb, embeds);
  gemm0(embeds, Wihf_b, bih_f, gi_f, cSB, cG2, cE, cG2);
  gemm0(embeds, Wihb_b, bih_b, gi_b, cSB, cG2, cE, cG2);
  enc_rnn_k<<<dim3(8), dim3(512), 0, stream>>>(Whhf_b, Whhb_b, gi_f, gi_b, bhh_f, bhh_b,
                                               hfin, states);
  concat_k<<<dim3((cB * cH + 255) / 256), dim3(256), 0, stream>>>(
      hfin, hfin + (size_t)cB * cH2, hdec0_bf, hdec0_f);
  gemm0(hdec0_bf, W2_b, b2, hw2, cB, cH, cH, cH);
  {  // sgate: statesg = sigmoid(states@W1^T + b1 + hw2) * states
    GArgs ga{states, W1_b, b1, nullptr, statesg, hw2, states, nullptr, cSB, cH, cH, cH};
    int waves = (cSB / 64) * (cH / 64);
    gemm64_k<1><<<dim3((waves + 3) / 4), dim3(256), 0, stream>>>(ga);
  }
  gemm0(statesg, We_b, be, encproj, cSB, cM, cH, cM);

  // decoder
  for (int t = 0; t < cT - 1; ++t) {
    const bf16* hin_bf = (t == 0) ? hdec0_bf : ((t & 1) ? hping_bf0 : hping_bf1);
    const float* hin_f = (t == 0) ? hdec0_f : ((t & 1) ? hping_f0 : hping_f1);
    bf16* hout_bf = (t & 1) ? hping_bf1 : hping_bf0;
    float* hout_f = (t & 1) ? hping_f1 : hping_f0;

    attn_k<<<dim3(cB), dim3(256), 0, stream>>>(hin_bf, Wd, bd, Wo, bo, encproj, statesg,
                                               emb, trg, t, xh);
    gemm0(xh, Wp_b, bp, g4, cB, cN4, cKcat, cN4);
    gru_gate_k<<<dim3((cB * cH + 255) / 256), dim3(256), 0, stream>>>(g4, hin_f, hout_f, hout_bf);
    {  // logits partials
      GArgs ga{hout_bf, Wv_b, bv, nullptr, nullptr, nullptr, nullptr, partials, cB, cV, cH, 0};
      int waves = cNTV;  // 782
      gemm64_k<3><<<dim3((waves + 3) / 4), dim3(256), 0, stream>>>(ga);
    }
    loss_k<<<dim3(1), dim3(1024), 0, stream>>>(partials, hout_bf, Wv, bv, trg, t, accum, out);
  }
}